// Round 14
// baseline (122.343 us; speedup 1.0000x reference)
//
#include <hip/hip_runtime.h>
#include <stdint.h>

#define S_LEN 4096
#define NHEADS 16
#define DHEAD 64
#define EMB 1024
#define NBATCH 4
#define NBH (NBATCH * NHEADS)   // 64

typedef unsigned short u16t;
typedef __attribute__((ext_vector_type(8))) short short8;
typedef __attribute__((ext_vector_type(4))) float f32x4;

__device__ __forceinline__ u16t f2bf(float f) {
  unsigned int x = __float_as_uint(f);
  x += 0x7fffu + ((x >> 16) & 1u);
  return (u16t)(x >> 16);
}
__device__ __forceinline__ unsigned int pack2(float a, float b) {
  return (unsigned int)f2bf(a) | ((unsigned int)f2bf(b) << 16);
}
__device__ __forceinline__ float bf2f(u16t u) { return __uint_as_float(((unsigned int)u) << 16); }
__device__ __forceinline__ float phifn(float v) { return v > 0.f ? v + 1.f : __expf(v); }

// ---- stage 8192B bf16 weight (pre-swizzled in global) via global_load_lds --
__device__ __forceinline__ void stage_w8k(const u16t* __restrict__ wg,
                                          u16t* __restrict__ lds, int t) {
#pragma unroll
  for (int c = 0; c < 2; ++c) {
    const u16t* src = wg + (size_t)(c * 256 + t) * 8;
    char* dst = (char*)lds + c * 4096 + ((t >> 6) << 10);
    __builtin_amdgcn_global_load_lds((const __attribute__((address_space(1))) unsigned int*)src,
                                     (__attribute__((address_space(3))) unsigned int*)dst,
                                     16, 0, 0);
  }
}

// ---------------- Kprep: Wq/Wk/Wv -> pre-swizzled bf16 WT; Wo -> WoT --------
__global__ __launch_bounds__(256) void la_wprep(const float* __restrict__ Wq,
                                                const float* __restrict__ Wk,
                                                const float* __restrict__ Wv,
                                                const float* __restrict__ Wo,
                                                u16t* __restrict__ WqT,
                                                u16t* __restrict__ WkT,
                                                u16t* __restrict__ WvT,
                                                u16t* __restrict__ WoT) {
  __shared__ float tmp[64][65];
  int blk = blockIdx.x;
  int t = threadIdx.x;
  if (blk < 48) {
    int mat = blk >> 4, h = blk & 15;
    const float* src = (mat == 0 ? Wq : (mat == 1 ? Wk : Wv)) + (size_t)h * 4096;
    u16t* dst = (mat == 0 ? WqT : (mat == 1 ? WkT : WvT)) + (size_t)h * 4096;
#pragma unroll
    for (int p = 0; p < 16; ++p) {
      int i = p * 256 + t;
      tmp[i >> 6][i & 63] = src[i];
    }
    __syncthreads();
#pragma unroll
    for (int p = 0; p < 16; ++p) {
      int i = p * 256 + t;
      int e = i >> 6, r = i & 63, o = r >> 3, j = r & 7;
      dst[i] = f2bf(tmp[((o ^ (e & 7)) << 3) + j][e]);
    }
  } else {
    int bb = blk - 48;
    int n0 = (bb & 15) * 64, k0 = (bb >> 4) * 64;
    int tx = t & 63, ty = t >> 6;  // 64 x 4
    for (int r = ty; r < 64; r += 4) tmp[r][tx] = Wo[(size_t)(k0 + r) * EMB + n0 + tx];
    __syncthreads();
    for (int r = ty; r < 64; r += 4)
      WoT[(size_t)(n0 + r) * EMB + k0 + tx] = f2bf(tmp[tx][r]);
  }
}

// ---------------- K1: q,k,v proj (MFMA) 64-row chunks; phiq; kv/ksum --------
// R9-proven config: 512 blocks x 8 chunks, 53 KB LDS.
__global__ __launch_bounds__(256) void la_kvq5(const float* __restrict__ q,
                                               const u16t* __restrict__ WqT,
                                               const u16t* __restrict__ WkT,
                                               const u16t* __restrict__ WvT,
                                               u16t* __restrict__ phiq,
                                               float* __restrict__ kvpart,
                                               float* __restrict__ kspart) {
  __shared__ u16t xs[64 * 72];
  __shared__ u16t wq[4096];
  __shared__ u16t wk[4096];
  __shared__ u16t wv[4096];
  __shared__ u16t pkT[64 * 72];
  __shared__ u16t vT[64 * 72];
  __shared__ float ksp4[4][64];
  int blk = blockIdx.x;
  int bh = blk >> 3, tile = blk & 7;
  int b = bh >> 4, h = bh & 15;
  int s0 = tile << 9;  // 512 rows per block, 8 chunks of 64
  int t = threadIdx.x;
  int wave = t >> 6, lane = t & 63, l16 = lane & 15, g = lane >> 4;

  stage_w8k(WqT + (size_t)h * 4096, wq, t);
  stage_w8k(WkT + (size_t)h * 4096, wk, t);
  stage_w8k(WvT + (size_t)h * 4096, wv, t);

  const float* xg = q + ((size_t)b * S_LEN + s0) * EMB + h * 64;
  int pr_r = t >> 4, pr_c4 = (t & 15) * 4;

  float4 pre[4];
#pragma unroll
  for (int i = 0; i < 4; ++i)
    pre[i] = *(const float4*)(xg + (size_t)(i * 16 + pr_r) * EMB + pr_c4);

  f32x4 kacc[4];
#pragma unroll
  for (int n = 0; n < 4; ++n) kacc[n] = 0.f;
  float ks_acc = 0.f;
  int ks_e = t & 63, ks_q = t >> 6;

  for (int c = 0; c < 8; ++c) {
    if (c) __syncthreads();
#pragma unroll
    for (int i = 0; i < 4; ++i) {
      uint2 p;
      p.x = pack2(pre[i].x, pre[i].y);
      p.y = pack2(pre[i].z, pre[i].w);
      *(uint2*)(&xs[(i * 16 + pr_r) * 72 + pr_c4]) = p;
    }
    if (c < 7) {
#pragma unroll
      for (int i = 0; i < 4; ++i)
        pre[i] = *(const float4*)(xg + (size_t)((c + 1) * 64 + i * 16 + pr_r) * EMB + pr_c4);
    }
    __syncthreads();

    f32x4 aQ[4], aK[4], aV[4];
#pragma unroll
    for (int n = 0; n < 4; ++n) { aQ[n] = 0.f; aK[n] = 0.f; aV[n] = 0.f; }
    short8 af[2];
#pragma unroll
    for (int kk = 0; kk < 2; ++kk)
      af[kk] = *(const short8*)(&xs[(wave * 16 + l16) * 72 + kk * 32 + g * 8]);
#pragma unroll
    for (int n = 0; n < 4; ++n) {
      int e = n * 16 + l16;
#pragma unroll
      for (int kk = 0; kk < 2; ++kk) {
        int op = (kk * 4 + g) ^ (l16 & 7);
        short8 bQ = *(const short8*)(&wq[e * 64 + op * 8]);
        short8 bK = *(const short8*)(&wk[e * 64 + op * 8]);
        short8 bV = *(const short8*)(&wv[e * 64 + op * 8]);
        aQ[n] = __builtin_amdgcn_mfma_f32_16x16x32_bf16(af[kk], bQ, aQ[n], 0, 0, 0);
        aK[n] = __builtin_amdgcn_mfma_f32_16x16x32_bf16(af[kk], bK, aK[n], 0, 0, 0);
        aV[n] = __builtin_amdgcn_mfma_f32_16x16x32_bf16(af[kk], bV, aV[n], 0, 0, 0);
      }
    }
    __syncthreads();

#pragma unroll
    for (int n = 0; n < 4; ++n) {
      int e = n * 16 + l16;
      int sb = wave * 16 + g * 4;
      uint2 pk2, vv2;
      pk2.x = pack2(phifn(aK[n][0]), phifn(aK[n][1]));
      pk2.y = pack2(phifn(aK[n][2]), phifn(aK[n][3]));
      vv2.x = pack2(aV[n][0], aV[n][1]);
      vv2.y = pack2(aV[n][2], aV[n][3]);
      *(uint2*)(&pkT[e * 72 + sb]) = pk2;
      *(uint2*)(&vT[e * 72 + sb]) = vv2;
#pragma unroll
      for (int j = 0; j < 4; ++j) xs[(sb + j) * 72 + e] = f2bf(phifn(aQ[n][j]));
    }
    __syncthreads();

#pragma unroll
    for (int i = 0; i < 2; ++i) {
      int slot = i * 256 + t;
      int r = slot >> 3, cc = (slot & 7) * 8;
      *(uint4*)(phiq + ((size_t)bh * S_LEN + s0 + c * 64 + r) * 64 + cc) =
          *(const uint4*)(&xs[r * 72 + cc]);
    }
#pragma unroll
    for (int ks = 0; ks < 2; ++ks) {
      short8 pa = *(const short8*)(&pkT[(wave * 16 + l16) * 72 + ks * 32 + g * 8]);
#pragma unroll
      for (int n = 0; n < 4; ++n) {
        short8 vb = *(const short8*)(&vT[(n * 16 + l16) * 72 + ks * 32 + g * 8]);
        kacc[n] = __builtin_amdgcn_mfma_f32_16x16x32_bf16(pa, vb, kacc[n], 0, 0, 0);
      }
    }
#pragma unroll
    for (int i = 0; i < 4; ++i) {
      uint2 u = *(const uint2*)(&pkT[ks_e * 72 + ks_q * 16 + i * 4]);
      ks_acc += bf2f((u16t)(u.x & 0xffff)) + bf2f((u16t)(u.x >> 16)) +
                bf2f((u16t)(u.y & 0xffff)) + bf2f((u16t)(u.y >> 16));
    }
  }

  float* kp = kvpart + (size_t)blk * 4096;
#pragma unroll
  for (int n = 0; n < 4; ++n)
#pragma unroll
    for (int j = 0; j < 4; ++j)
      kp[(wave * 16 + g * 4 + j) * 64 + n * 16 + l16] = kacc[n][j];

  ksp4[ks_q][ks_e] = ks_acc;
  __syncthreads();
  if (t < 64)
    kspart[(size_t)blk * 64 + t] = ksp4[0][t] + ksp4[1][t] + ksp4[2][t] + ksp4[3][t];
}

// ---------------- K2: merged scale (1024 blks, self-ksum) + W2T (64 blks) ---
__global__ __launch_bounds__(256) void la_rs(const float* __restrict__ kvpart,
                                             const float* __restrict__ kspart,
                                             const u16t* __restrict__ WoT,
                                             const u16t* __restrict__ phiq,
                                             u16t* __restrict__ W2T,
                                             u16t* __restrict__ phiq2) {
  int blk = blockIdx.x;
  int t = threadIdx.x;
  if (blk < 1024) {
    // ---- scale path: z = phiq . ksum; phiq2 = phiq/(z+eps), [s][h*64+d'] ---
    __shared__ float ks[64];
    int bh = blk >> 4, sl = blk & 15;
    int b = bh >> 4, h = bh & 15;
    int s0 = sl * 256;
    if (t < 64) {
      // self-computed ksum: identical summation order to la_red3 (p=0..7)
      float a = 0.f;
      for (int p = 0; p < 8; ++p) a += kspart[((size_t)bh * 8 + p) * 64 + t];
      ks[t] = a;
    }
    __syncthreads();
    int c16 = t & 15, rg = t >> 4;
#pragma unroll 2
    for (int it = 0; it < 16; ++it) {
      int s = s0 + it * 16 + rg;
      uint2 u = *(const uint2*)(phiq + ((size_t)bh * S_LEN + s) * 64 + c16 * 4);
      float f0 = bf2f((u16t)(u.x & 0xffff)), f1 = bf2f((u16t)(u.x >> 16));
      float f2 = bf2f((u16t)(u.y & 0xffff)), f3 = bf2f((u16t)(u.y >> 16));
      float zp = f0 * ks[c16 * 4] + f1 * ks[c16 * 4 + 1] + f2 * ks[c16 * 4 + 2] + f3 * ks[c16 * 4 + 3];
      zp += __shfl_xor(zp, 1);
      zp += __shfl_xor(zp, 2);
      zp += __shfl_xor(zp, 4);
      zp += __shfl_xor(zp, 8);
      float inv = 1.f / (zp + 1e-6f);
      uint2 o;
      o.x = pack2(f0 * inv, f1 * inv);
      o.y = pack2(f2 * inv, f3 * inv);
      *(uint2*)(phiq2 + ((size_t)(b * S_LEN + s)) * EMB + h * 64 + c16 * 4) = o;
    }
  } else {
    // ---- W2T path: reduce kvpart; W2T[b][e][h*64+d'] = WoT_h @ kv ----------
    __shared__ float kvs[64][65];
    __shared__ u16t aT[256 * 72];
    int bh = blk - 1024;
    int b = bh >> 4, h = bh & 15;
    int wave = t >> 6, lane = t & 63, l16 = lane & 15, g = lane >> 4;

    float acc[16];
#pragma unroll
    for (int i = 0; i < 16; ++i) acc[i] = 0.f;
    for (int p = 0; p < 8; ++p) {
      const float* base = kvpart + ((size_t)bh * 8 + p) * 4096;
#pragma unroll
      for (int i = 0; i < 16; ++i) acc[i] += base[i * 256 + t];
    }
#pragma unroll
    for (int i = 0; i < 16; ++i) {
      int idx = i * 256 + t;
      kvs[idx >> 6][idx & 63] = acc[i];
    }
    __syncthreads();

    short8 kvbf[4][2];
#pragma unroll
    for (int n = 0; n < 4; ++n)
#pragma unroll
      for (int kk = 0; kk < 2; ++kk) {
        u16t* pp = (u16t*)&kvbf[n][kk];
#pragma unroll
        for (int i = 0; i < 8; ++i) pp[i] = f2bf(kvs[n * 16 + l16][kk * 32 + g * 8 + i]);
      }

    for (int ec = 0; ec < 4; ++ec) {
      if (ec) __syncthreads();
#pragma unroll
      for (int p = 0; p < 8; ++p) {
        int slot = p * 256 + t;
        int r = slot >> 3, cc = (slot & 7) * 8;
        *(uint4*)(&aT[r * 72 + cc]) =
            *(const uint4*)(WoT + (size_t)(ec * 256 + r) * 1024 + h * 64 + cc);
      }
      __syncthreads();
      f32x4 c2[4][4];
#pragma unroll
      for (int mi = 0; mi < 4; ++mi)
#pragma unroll
        for (int n = 0; n < 4; ++n) c2[mi][n] = 0.f;
#pragma unroll
      for (int kk = 0; kk < 2; ++kk)
#pragma unroll
        for (int mi = 0; mi < 4; ++mi) {
          short8 afr = *(const short8*)(&aT[(wave * 64 + mi * 16 + l16) * 72 + kk * 32 + g * 8]);
#pragma unroll
          for (int n = 0; n < 4; ++n)
            c2[mi][n] = __builtin_amdgcn_mfma_f32_16x16x32_bf16(afr, kvbf[n][kk], c2[mi][n], 0, 0, 0);
        }
      __syncthreads();
#pragma unroll
      for (int mi = 0; mi < 4; ++mi)
#pragma unroll
        for (int n = 0; n < 4; ++n)
#pragma unroll
          for (int j = 0; j < 4; ++j)
            aT[(wave * 64 + mi * 16 + g * 4 + j) * 72 + n * 16 + l16] = f2bf(c2[mi][n][j]);
      __syncthreads();
#pragma unroll
      for (int p = 0; p < 8; ++p) {
        int slot = p * 256 + t;
        int r = slot >> 3, cc = (slot & 7) * 8;
        *(uint4*)(W2T + ((size_t)b << 20) + (size_t)(ec * 256 + r) * 1024 + h * 64 + cc) =
            *(const uint4*)(&aT[r * 72 + cc]);
      }
    }
  }
}

// ---------------- K4: out = phiq2(bf16) @ W2T[b]  (256x256 8-phase, R6) -----
__device__ __forceinline__ void stage_half(const u16t* __restrict__ gbase,
                                           u16t* __restrict__ lbuf,
                                           int half, int t) {
#pragma unroll
  for (int it = 0; it < 2; ++it) {
    int slot = it * 512 + t;
    int row = half * 128 + (slot >> 3);
    int oct = slot & 7;
    const u16t* src = gbase + (size_t)row * EMB + (((oct ^ (row & 7)) << 3));
    char* dst = (char*)lbuf + ((half * 128 + it * 64 + ((t >> 6) << 3)) << 7);
    __builtin_amdgcn_global_load_lds((const __attribute__((address_space(1))) unsigned int*)src,
                                     (__attribute__((address_space(3))) unsigned int*)dst,
                                     16, 0, 0);
  }
}

#define GFENCE asm volatile("" ::: "memory")

#define LOAD_A(QM)                                                              \
  _Pragma("unroll") for (int mi = 0; mi < 4; ++mi) _Pragma("unroll")            \
      for (int kk = 0; kk < 2; ++kk) {                                          \
    int rr = (QM) * 128 + wr2 * 64 + mi * 16 + l16;                             \
    afr[mi][kk] = *(const short8*)((const char*)Acur + rr * 128 +               \
                                   ((((kk << 2) | g) ^ (rr & 7)) << 4));        \
  }
#define LOAD_B(QN, DST)                                                         \
  _Pragma("unroll") for (int ni = 0; ni < 2; ++ni) _Pragma("unroll")            \
      for (int kk = 0; kk < 2; ++kk) {                                          \
    int rr = (QN) * 128 + wc2 * 32 + ni * 16 + l16;                             \
    DST[ni][kk] = *(const short8*)((const char*)Bcur + rr * 128 +               \
                                   ((((kk << 2) | g) ^ (rr & 7)) << 4));        \
  }
#define MFMA_Q(QM, QN, BF)                                                      \
  __builtin_amdgcn_s_setprio(1);                                                \
  _Pragma("unroll") for (int mi = 0; mi < 4; ++mi) _Pragma("unroll")            \
      for (int ni = 0; ni < 2; ++ni) {                                          \
    acc[QM][QN][mi][ni] = __builtin_amdgcn_mfma_f32_16x16x32_bf16(              \
        afr[mi][0], BF[ni][0], acc[QM][QN][mi][ni], 0, 0, 0);                   \
    acc[QM][QN][mi][ni] = __builtin_amdgcn_mfma_f32_16x16x32_bf16(              \
        afr[mi][1], BF[ni][1], acc[QM][QN][mi][ni], 0, 0, 0);                   \
  }                                                                             \
  __builtin_amdgcn_s_setprio(0);

#define BAR()                      \
  __builtin_amdgcn_s_barrier();    \
  GFENCE

__global__ __launch_bounds__(512, 2) void la_gemm9(const u16t* __restrict__ A,
                                                   const u16t* __restrict__ W2T,
                                                   float* __restrict__ C) {
  __shared__ u16t Al[2][16384];
  __shared__ u16t Bl[2][16384];
  int t = threadIdx.x;
  int bid = blockIdx.x;
  int swz = ((bid & 7) << 5) + (bid >> 3);  // XCD swizzle, 256 % 8 == 0
  int mt = swz >> 2, nt = swz & 3;
  const int M0 = mt * 256, N0 = nt * 256;
  const int b = mt >> 4;
  int wave = t >> 6, lane = t & 63;
  int l16 = lane & 15, g = lane >> 4;
  int wr2 = wave >> 2, wc2 = wave & 3;

  f32x4 acc[2][2][4][2];
#pragma unroll
  for (int qm = 0; qm < 2; ++qm)
#pragma unroll
    for (int qn = 0; qn < 2; ++qn)
#pragma unroll
      for (int mi = 0; mi < 4; ++mi)
#pragma unroll
        for (int ni = 0; ni < 2; ++ni) acc[qm][qn][mi][ni] = 0.f;

  const u16t* Asrc = A + (size_t)M0 * EMB;
  const u16t* Bsrc = W2T + ((size_t)b << 20) + (size_t)N0 * EMB;

  // prologue: tile 0 -> buf 0 (need-order), keep Bh1/Ah1 in flight
  stage_half(Asrc, Al[0], 0, t);
  stage_half(Bsrc, Bl[0], 0, t);
  stage_half(Bsrc, Bl[0], 1, t);
  stage_half(Asrc, Al[0], 1, t);
  asm volatile("s_waitcnt vmcnt(4)" ::: "memory");
  BAR();

  short8 afr[4][2], bf0[2][2], bf1[2][2];

  for (int kt = 0; kt < 15; ++kt) {
    const u16t* Acur = Al[kt & 1];
    const u16t* Bcur = Bl[kt & 1];
    u16t* Anxt = Al[(kt + 1) & 1];
    u16t* Bnxt = Bl[(kt + 1) & 1];
    const u16t* An = Asrc + (kt + 1) * 64;
    const u16t* Bn = Bsrc + (kt + 1) * 64;
    // ph0: Q00
    LOAD_A(0);
    LOAD_B(0, bf0);
    stage_half(An, Anxt, 0, t);
    stage_half(Bn, Bnxt, 0, t);
    asm volatile("s_waitcnt vmcnt(6)" ::: "memory");
    BAR();
    MFMA_Q(0, 0, bf0);
    GFENCE;
    BAR();
    // ph1: Q01
    LOAD_B(1, bf1);
    stage_half(Bn, Bnxt, 1, t);
    asm volatile("s_waitcnt vmcnt(6)" ::: "memory");
    BAR();
    MFMA_Q(0, 1, bf1);
    GFENCE;
    BAR();
    // ph2: Q11
    LOAD_A(1);
    stage_half(An, Anxt, 1, t);
    BAR();
    MFMA_Q(1, 1, bf1);
    GFENCE;
    BAR();
    // ph3: Q10
    asm volatile("s_waitcnt vmcnt(4)" ::: "memory");
    BAR();
    MFMA_Q(1, 0, bf0);
    GFENCE;
    BAR();
  }
  {  // peeled last tile (kt = 15)
    const u16t* Acur = Al[1];
    const u16t* Bcur = Bl[1];
    LOAD_A(0);
    LOAD_B(0, bf0);
    asm volatile("s_waitcnt vmcnt(2)" ::: "memory");
    BAR();
    MFMA_Q(0, 0, bf0);
    GFENCE;
    BAR();
    LOAD_B(1, bf1);
    asm volatile("s_waitcnt vmcnt(0)" ::: "memory");
    BAR();
    MFMA_Q(0, 1, bf1);
    GFENCE;
    BAR();
    LOAD_A(1);
    BAR();
    MFMA_Q(1, 1, bf1);
    GFENCE;
    BAR();
    BAR();
    MFMA_Q(1, 0, bf0);
    GFENCE;
  }

#pragma unroll
  for (int qm = 0; qm < 2; ++qm)
#pragma unroll
    for (int qn = 0; qn < 2; ++qn)
#pragma unroll
      for (int mi = 0; mi < 4; ++mi)
#pragma unroll
        for (int ni = 0; ni < 2; ++ni)
#pragma unroll
          for (int j = 0; j < 4; ++j) {
            int row = M0 + qm * 128 + wr2 * 64 + mi * 16 + g * 4 + j;
            int col = N0 + qn * 128 + wc2 * 32 + ni * 16 + l16;
            C[(size_t)row * EMB + col] = acc[qm][qn][mi][ni][j];
          }
}

// ---------------- launch ----------------------------------------------------
extern "C" void kernel_launch(void* const* d_in, const int* in_sizes, int n_in,
                              void* d_out, int out_size, void* d_ws, size_t ws_size,
                              hipStream_t stream) {
  const float* query = (const float*)d_in[0];
  const float* Wq = (const float*)d_in[1];
  const float* Wk = (const float*)d_in[2];
  const float* Wv = (const float*)d_in[3];
  const float* Wo = (const float*)d_in[4];
  float* out = (float*)d_out;
  char* ws = (char*)d_ws;

  // workspace carve (bytes)
  u16t* WoT     = (u16t*)(ws);                 //  2,097,152
  u16t* WqT     = (u16t*)(ws + 2097152);       //    131,072
  u16t* WkT     = (u16t*)(ws + 2228224);       //    131,072
  u16t* WvT     = (u16t*)(ws + 2359296);       //    131,072
  u16t* phiq    = (u16t*)(ws + 2490368);       // 33,554,432  [bh][s][64]
  float* kvpart = (float*)(ws + 36044800);     //  8,388,608  [512][4096]
  float* kspart = (float*)(ws + 44433408);     //    131,072
  u16t* W2T     = (u16t*)(ws + 44564480);      //  8,388,608  [b][e][k]
  u16t* phiq2   = (u16t*)(ws + 52953088);      // 33,554,432  [s][1024]
  // total ~86.5 MB

  la_wprep<<<304, 256, 0, stream>>>(Wq, Wk, Wv, Wo, WqT, WkT, WvT, WoT);
  la_kvq5<<<512, 256, 0, stream>>>(query, WqT, WkT, WvT, phiq, kvpart, kspart);
  la_rs<<<1088, 256, 0, stream>>>(kvpart, kspart, WoT, phiq, W2T, phiq2);
  la_gemm9<<<256, 512, 0, stream>>>(phiq2, W2T, out);
}

// Round 15
// 105.721 us; speedup vs baseline: 1.1572x; 1.1572x over previous
//
#include <hip/hip_runtime.h>
#include <stdint.h>

#define S_LEN 4096
#define NHEADS 16
#define DHEAD 64
#define EMB 1024
#define NBATCH 4
#define NBH (NBATCH * NHEADS)   // 64

typedef unsigned short u16t;
typedef __attribute__((ext_vector_type(8))) short short8;
typedef __attribute__((ext_vector_type(4))) float f32x4;

__device__ __forceinline__ u16t f2bf(float f) {
  unsigned int x = __float_as_uint(f);
  x += 0x7fffu + ((x >> 16) & 1u);
  return (u16t)(x >> 16);
}
__device__ __forceinline__ unsigned int pack2(float a, float b) {
  return (unsigned int)f2bf(a) | ((unsigned int)f2bf(b) << 16);
}
__device__ __forceinline__ float bf2f(u16t u) { return __uint_as_float(((unsigned int)u) << 16); }
__device__ __forceinline__ float phifn(float v) { return v > 0.f ? v + 1.f : __expf(v); }

// ---- stage 8192B bf16 weight (pre-swizzled in global) via global_load_lds --
__device__ __forceinline__ void stage_w8k(const u16t* __restrict__ wg,
                                          u16t* __restrict__ lds, int t) {
#pragma unroll
  for (int c = 0; c < 2; ++c) {
    const u16t* src = wg + (size_t)(c * 256 + t) * 8;
    char* dst = (char*)lds + c * 4096 + ((t >> 6) << 10);
    __builtin_amdgcn_global_load_lds((const __attribute__((address_space(1))) unsigned int*)src,
                                     (__attribute__((address_space(3))) unsigned int*)dst,
                                     16, 0, 0);
  }
}

// ---------------- Kprep: Wq/Wk/Wv -> pre-swizzled bf16 WT; Wo -> WoT --------
__global__ __launch_bounds__(256) void la_wprep(const float* __restrict__ Wq,
                                                const float* __restrict__ Wk,
                                                const float* __restrict__ Wv,
                                                const float* __restrict__ Wo,
                                                u16t* __restrict__ WqT,
                                                u16t* __restrict__ WkT,
                                                u16t* __restrict__ WvT,
                                                u16t* __restrict__ WoT) {
  __shared__ float tmp[64][65];
  int blk = blockIdx.x;
  int t = threadIdx.x;
  if (blk < 48) {
    int mat = blk >> 4, h = blk & 15;
    const float* src = (mat == 0 ? Wq : (mat == 1 ? Wk : Wv)) + (size_t)h * 4096;
    u16t* dst = (mat == 0 ? WqT : (mat == 1 ? WkT : WvT)) + (size_t)h * 4096;
#pragma unroll
    for (int p = 0; p < 16; ++p) {
      int i = p * 256 + t;
      tmp[i >> 6][i & 63] = src[i];
    }
    __syncthreads();
#pragma unroll
    for (int p = 0; p < 16; ++p) {
      int i = p * 256 + t;
      int e = i >> 6, r = i & 63, o = r >> 3, j = r & 7;
      dst[i] = f2bf(tmp[((o ^ (e & 7)) << 3) + j][e]);
    }
  } else {
    int bb = blk - 48;
    int n0 = (bb & 15) * 64, k0 = (bb >> 4) * 64;
    int tx = t & 63, ty = t >> 6;  // 64 x 4
    for (int r = ty; r < 64; r += 4) tmp[r][tx] = Wo[(size_t)(k0 + r) * EMB + n0 + tx];
    __syncthreads();
    for (int r = ty; r < 64; r += 4)
      WoT[(size_t)(n0 + r) * EMB + k0 + tx] = f2bf(tmp[tx][r]);
  }
}

// ---------------- K1: q,k,v proj (MFMA) 64-row chunks; phiq; kv/ksum --------
// R9-proven config: 512 blocks x 8 chunks, 53 KB LDS.
__global__ __launch_bounds__(256) void la_kvq5(const float* __restrict__ q,
                                               const u16t* __restrict__ WqT,
                                               const u16t* __restrict__ WkT,
                                               const u16t* __restrict__ WvT,
                                               u16t* __restrict__ phiq,
                                               float* __restrict__ kvpart,
                                               float* __restrict__ kspart) {
  __shared__ u16t xs[64 * 72];
  __shared__ u16t wq[4096];
  __shared__ u16t wk[4096];
  __shared__ u16t wv[4096];
  __shared__ u16t pkT[64 * 72];
  __shared__ u16t vT[64 * 72];
  __shared__ float ksp4[4][64];
  int blk = blockIdx.x;
  int bh = blk >> 3, tile = blk & 7;
  int b = bh >> 4, h = bh & 15;
  int s0 = tile << 9;  // 512 rows per block, 8 chunks of 64
  int t = threadIdx.x;
  int wave = t >> 6, lane = t & 63, l16 = lane & 15, g = lane >> 4;

  stage_w8k(WqT + (size_t)h * 4096, wq, t);
  stage_w8k(WkT + (size_t)h * 4096, wk, t);
  stage_w8k(WvT + (size_t)h * 4096, wv, t);

  const float* xg = q + ((size_t)b * S_LEN + s0) * EMB + h * 64;
  int pr_r = t >> 4, pr_c4 = (t & 15) * 4;

  float4 pre[4];
#pragma unroll
  for (int i = 0; i < 4; ++i)
    pre[i] = *(const float4*)(xg + (size_t)(i * 16 + pr_r) * EMB + pr_c4);

  f32x4 kacc[4];
#pragma unroll
  for (int n = 0; n < 4; ++n) kacc[n] = 0.f;
  float ks_acc = 0.f;
  int ks_e = t & 63, ks_q = t >> 6;

  for (int c = 0; c < 8; ++c) {
    if (c) __syncthreads();
#pragma unroll
    for (int i = 0; i < 4; ++i) {
      uint2 p;
      p.x = pack2(pre[i].x, pre[i].y);
      p.y = pack2(pre[i].z, pre[i].w);
      *(uint2*)(&xs[(i * 16 + pr_r) * 72 + pr_c4]) = p;
    }
    if (c < 7) {
#pragma unroll
      for (int i = 0; i < 4; ++i)
        pre[i] = *(const float4*)(xg + (size_t)((c + 1) * 64 + i * 16 + pr_r) * EMB + pr_c4);
    }
    __syncthreads();

    f32x4 aQ[4], aK[4], aV[4];
#pragma unroll
    for (int n = 0; n < 4; ++n) { aQ[n] = 0.f; aK[n] = 0.f; aV[n] = 0.f; }
    short8 af[2];
#pragma unroll
    for (int kk = 0; kk < 2; ++kk)
      af[kk] = *(const short8*)(&xs[(wave * 16 + l16) * 72 + kk * 32 + g * 8]);
#pragma unroll
    for (int n = 0; n < 4; ++n) {
      int e = n * 16 + l16;
#pragma unroll
      for (int kk = 0; kk < 2; ++kk) {
        int op = (kk * 4 + g) ^ (l16 & 7);
        short8 bQ = *(const short8*)(&wq[e * 64 + op * 8]);
        short8 bK = *(const short8*)(&wk[e * 64 + op * 8]);
        short8 bV = *(const short8*)(&wv[e * 64 + op * 8]);
        aQ[n] = __builtin_amdgcn_mfma_f32_16x16x32_bf16(af[kk], bQ, aQ[n], 0, 0, 0);
        aK[n] = __builtin_amdgcn_mfma_f32_16x16x32_bf16(af[kk], bK, aK[n], 0, 0, 0);
        aV[n] = __builtin_amdgcn_mfma_f32_16x16x32_bf16(af[kk], bV, aV[n], 0, 0, 0);
      }
    }
    __syncthreads();

#pragma unroll
    for (int n = 0; n < 4; ++n) {
      int e = n * 16 + l16;
      int sb = wave * 16 + g * 4;
      uint2 pk2, vv2;
      pk2.x = pack2(phifn(aK[n][0]), phifn(aK[n][1]));
      pk2.y = pack2(phifn(aK[n][2]), phifn(aK[n][3]));
      vv2.x = pack2(aV[n][0], aV[n][1]);
      vv2.y = pack2(aV[n][2], aV[n][3]);
      *(uint2*)(&pkT[e * 72 + sb]) = pk2;
      *(uint2*)(&vT[e * 72 + sb]) = vv2;
#pragma unroll
      for (int j = 0; j < 4; ++j) xs[(sb + j) * 72 + e] = f2bf(phifn(aQ[n][j]));
    }
    __syncthreads();

#pragma unroll
    for (int i = 0; i < 2; ++i) {
      int slot = i * 256 + t;
      int r = slot >> 3, cc = (slot & 7) * 8;
      *(uint4*)(phiq + ((size_t)bh * S_LEN + s0 + c * 64 + r) * 64 + cc) =
          *(const uint4*)(&xs[r * 72 + cc]);
    }
#pragma unroll
    for (int ks = 0; ks < 2; ++ks) {
      short8 pa = *(const short8*)(&pkT[(wave * 16 + l16) * 72 + ks * 32 + g * 8]);
#pragma unroll
      for (int n = 0; n < 4; ++n) {
        short8 vb = *(const short8*)(&vT[(n * 16 + l16) * 72 + ks * 32 + g * 8]);
        kacc[n] = __builtin_amdgcn_mfma_f32_16x16x32_bf16(pa, vb, kacc[n], 0, 0, 0);
      }
    }
#pragma unroll
    for (int i = 0; i < 4; ++i) {
      uint2 u = *(const uint2*)(&pkT[ks_e * 72 + ks_q * 16 + i * 4]);
      ks_acc += bf2f((u16t)(u.x & 0xffff)) + bf2f((u16t)(u.x >> 16)) +
                bf2f((u16t)(u.y & 0xffff)) + bf2f((u16t)(u.y >> 16));
    }
  }

  float* kp = kvpart + (size_t)blk * 4096;
#pragma unroll
  for (int n = 0; n < 4; ++n)
#pragma unroll
    for (int j = 0; j < 4; ++j)
      kp[(wave * 16 + g * 4 + j) * 64 + n * 16 + l16] = kacc[n][j];

  ksp4[ks_q][ks_e] = ks_acc;
  __syncthreads();
  if (t < 64)
    kspart[(size_t)blk * 64 + t] = ksp4[0][t] + ksp4[1][t] + ksp4[2][t] + ksp4[3][t];
}

// ---------------- K2: reduce partials (8/bh); W2T = WoT_h @ kv --------------
__global__ __launch_bounds__(256) void la_red3(const float* __restrict__ kvpart,
                                               const float* __restrict__ kspart,
                                               const u16t* __restrict__ WoT,
                                               float* __restrict__ ksum_g,
                                               u16t* __restrict__ W2T) {
  __shared__ float kvs[64][65];
  __shared__ u16t aT[256 * 72];
  int bh = blockIdx.x;
  int b = bh >> 4, h = bh & 15;
  int t = threadIdx.x, wave = t >> 6, lane = t & 63, l16 = lane & 15, g = lane >> 4;

  float acc[16];
#pragma unroll
  for (int i = 0; i < 16; ++i) acc[i] = 0.f;
  for (int p = 0; p < 8; ++p) {
    const float* base = kvpart + ((size_t)bh * 8 + p) * 4096;
#pragma unroll
    for (int i = 0; i < 16; ++i) acc[i] += base[i * 256 + t];
  }
#pragma unroll
  for (int i = 0; i < 16; ++i) {
    int idx = i * 256 + t;
    kvs[idx >> 6][idx & 63] = acc[i];
  }
  if (t < 64) {
    float a = 0.f;
    for (int p = 0; p < 8; ++p) a += kspart[((size_t)bh * 8 + p) * 64 + t];
    ksum_g[(size_t)bh * 64 + t] = a;
  }
  __syncthreads();

  short8 kvbf[4][2];
#pragma unroll
  for (int n = 0; n < 4; ++n)
#pragma unroll
    for (int kk = 0; kk < 2; ++kk) {
      u16t* pp = (u16t*)&kvbf[n][kk];
#pragma unroll
      for (int i = 0; i < 8; ++i) pp[i] = f2bf(kvs[n * 16 + l16][kk * 32 + g * 8 + i]);
    }

  for (int ec = 0; ec < 4; ++ec) {
    if (ec) __syncthreads();
#pragma unroll
    for (int p = 0; p < 8; ++p) {
      int slot = p * 256 + t;
      int r = slot >> 3, cc = (slot & 7) * 8;
      *(uint4*)(&aT[r * 72 + cc]) =
          *(const uint4*)(WoT + (size_t)(ec * 256 + r) * 1024 + h * 64 + cc);
    }
    __syncthreads();
    f32x4 c2[4][4];
#pragma unroll
    for (int mi = 0; mi < 4; ++mi)
#pragma unroll
      for (int n = 0; n < 4; ++n) c2[mi][n] = 0.f;
#pragma unroll
    for (int kk = 0; kk < 2; ++kk)
#pragma unroll
      for (int mi = 0; mi < 4; ++mi) {
        short8 afr = *(const short8*)(&aT[(wave * 64 + mi * 16 + l16) * 72 + kk * 32 + g * 8]);
#pragma unroll
        for (int n = 0; n < 4; ++n)
          c2[mi][n] = __builtin_amdgcn_mfma_f32_16x16x32_bf16(afr, kvbf[n][kk], c2[mi][n], 0, 0, 0);
      }
    __syncthreads();
#pragma unroll
    for (int mi = 0; mi < 4; ++mi)
#pragma unroll
      for (int n = 0; n < 4; ++n)
#pragma unroll
        for (int j = 0; j < 4; ++j)
          aT[(wave * 64 + mi * 16 + g * 4 + j) * 72 + n * 16 + l16] = f2bf(c2[mi][n][j]);
    __syncthreads();
#pragma unroll
    for (int p = 0; p < 8; ++p) {
      int slot = p * 256 + t;
      int r = slot >> 3, cc = (slot & 7) * 8;
      *(uint4*)(W2T + ((size_t)b << 20) + (size_t)(ec * 256 + r) * 1024 + h * 64 + cc) =
          *(const uint4*)(&aT[r * 72 + cc]);
    }
  }
}

// ---------------- K3: z = phiq . ksum; phiq2[s][h*64+d'] = phiq/(z+eps) -----
__global__ __launch_bounds__(256) void la_scale(const u16t* __restrict__ phiq,
                                                const float* __restrict__ ksum_g,
                                                u16t* __restrict__ phiq2) {
  __shared__ float ks[64];
  int blk = blockIdx.x;
  int bh = blk >> 4, sl = blk & 15;
  int b = bh >> 4, h = bh & 15;
  int s0 = sl * 256;
  int t = threadIdx.x;
  if (t < 64) ks[t] = ksum_g[(size_t)bh * 64 + t];
  __syncthreads();
  int c16 = t & 15, rg = t >> 4;
#pragma unroll 2
  for (int it = 0; it < 16; ++it) {
    int s = s0 + it * 16 + rg;
    uint2 u = *(const uint2*)(phiq + ((size_t)bh * S_LEN + s) * 64 + c16 * 4);
    float f0 = bf2f((u16t)(u.x & 0xffff)), f1 = bf2f((u16t)(u.x >> 16));
    float f2 = bf2f((u16t)(u.y & 0xffff)), f3 = bf2f((u16t)(u.y >> 16));
    float zp = f0 * ks[c16 * 4] + f1 * ks[c16 * 4 + 1] + f2 * ks[c16 * 4 + 2] + f3 * ks[c16 * 4 + 3];
    zp += __shfl_xor(zp, 1);
    zp += __shfl_xor(zp, 2);
    zp += __shfl_xor(zp, 4);
    zp += __shfl_xor(zp, 8);
    float inv = 1.f / (zp + 1e-6f);
    uint2 o;
    o.x = pack2(f0 * inv, f1 * inv);
    o.y = pack2(f2 * inv, f3 * inv);
    *(uint2*)(phiq2 + ((size_t)(b * S_LEN + s)) * EMB + h * 64 + c16 * 4) = o;
  }
}

// ---------------- K4: out = phiq2(bf16) @ W2T[b]  (256x256 8-phase) ---------
__device__ __forceinline__ void stage_half(const u16t* __restrict__ gbase,
                                           u16t* __restrict__ lbuf,
                                           int half, int t) {
#pragma unroll
  for (int it = 0; it < 2; ++it) {
    int slot = it * 512 + t;
    int row = half * 128 + (slot >> 3);
    int oct = slot & 7;
    const u16t* src = gbase + (size_t)row * EMB + (((oct ^ (row & 7)) << 3));
    char* dst = (char*)lbuf + ((half * 128 + it * 64 + ((t >> 6) << 3)) << 7);
    __builtin_amdgcn_global_load_lds((const __attribute__((address_space(1))) unsigned int*)src,
                                     (__attribute__((address_space(3))) unsigned int*)dst,
                                     16, 0, 0);
  }
}

#define GFENCE asm volatile("" ::: "memory")

#define LOAD_A(QM)                                                              \
  _Pragma("unroll") for (int mi = 0; mi < 4; ++mi) _Pragma("unroll")            \
      for (int kk = 0; kk < 2; ++kk) {                                          \
    int rr = (QM) * 128 + wr2 * 64 + mi * 16 + l16;                             \
    afr[mi][kk] = *(const short8*)((const char*)Acur + rr * 128 +               \
                                   ((((kk << 2) | g) ^ (rr & 7)) << 4));        \
  }
#define LOAD_B(QN, DST)                                                         \
  _Pragma("unroll") for (int ni = 0; ni < 2; ++ni) _Pragma("unroll")            \
      for (int kk = 0; kk < 2; ++kk) {                                          \
    int rr = (QN) * 128 + wc2 * 32 + ni * 16 + l16;                             \
    DST[ni][kk] = *(const short8*)((const char*)Bcur + rr * 128 +               \
                                   ((((kk << 2) | g) ^ (rr & 7)) << 4));        \
  }
#define MFMA_Q(QM, QN, BF)                                                      \
  __builtin_amdgcn_s_setprio(1);                                                \
  _Pragma("unroll") for (int mi = 0; mi < 4; ++mi) _Pragma("unroll")            \
      for (int ni = 0; ni < 2; ++ni) {                                          \
    acc[QM][QN][mi][ni] = __builtin_amdgcn_mfma_f32_16x16x32_bf16(              \
        afr[mi][0], BF[ni][0], acc[QM][QN][mi][ni], 0, 0, 0);                   \
    acc[QM][QN][mi][ni] = __builtin_amdgcn_mfma_f32_16x16x32_bf16(              \
        afr[mi][1], BF[ni][1], acc[QM][QN][mi][ni], 0, 0, 0);                   \
  }                                                                             \
  __builtin_amdgcn_s_setprio(0);

#define BAR()                      \
  __builtin_amdgcn_s_barrier();    \
  GFENCE

__global__ __launch_bounds__(512, 2) void la_gemm9(const u16t* __restrict__ A,
                                                   const u16t* __restrict__ W2T,
                                                   float* __restrict__ C) {
  __shared__ u16t Al[2][16384];
  __shared__ u16t Bl[2][16384];
  int t = threadIdx.x;
  int bid = blockIdx.x;
  int swz = ((bid & 7) << 5) + (bid >> 3);  // XCD swizzle, 256 % 8 == 0
  int mt = swz >> 2, nt = swz & 3;
  const int M0 = mt * 256, N0 = nt * 256;
  const int b = mt >> 4;
  int wave = t >> 6, lane = t & 63;
  int l16 = lane & 15, g = lane >> 4;
  int wr2 = wave >> 2, wc2 = wave & 3;

  f32x4 acc[2][2][4][2];
#pragma unroll
  for (int qm = 0; qm < 2; ++qm)
#pragma unroll
    for (int qn = 0; qn < 2; ++qn)
#pragma unroll
      for (int mi = 0; mi < 4; ++mi)
#pragma unroll
        for (int ni = 0; ni < 2; ++ni) acc[qm][qn][mi][ni] = 0.f;

  const u16t* Asrc = A + (size_t)M0 * EMB;
  const u16t* Bsrc = W2T + ((size_t)b << 20) + (size_t)N0 * EMB;

  // prologue: tile 0 -> buf 0 (need-order), keep Bh1/Ah1 in flight
  stage_half(Asrc, Al[0], 0, t);
  stage_half(Bsrc, Bl[0], 0, t);
  stage_half(Bsrc, Bl[0], 1, t);
  stage_half(Asrc, Al[0], 1, t);
  asm volatile("s_waitcnt vmcnt(4)" ::: "memory");
  BAR();

  short8 afr[4][2], bf0[2][2], bf1[2][2];

  for (int kt = 0; kt < 15; ++kt) {
    const u16t* Acur = Al[kt & 1];
    const u16t* Bcur = Bl[kt & 1];
    u16t* Anxt = Al[(kt + 1) & 1];
    u16t* Bnxt = Bl[(kt + 1) & 1];
    const u16t* An = Asrc + (kt + 1) * 64;
    const u16t* Bn = Bsrc + (kt + 1) * 64;
    // ph0: Q00
    LOAD_A(0);
    LOAD_B(0, bf0);
    stage_half(An, Anxt, 0, t);
    stage_half(Bn, Bnxt, 0, t);
    asm volatile("s_waitcnt vmcnt(6)" ::: "memory");
    BAR();
    MFMA_Q(0, 0, bf0);
    GFENCE;
    BAR();
    // ph1: Q01
    LOAD_B(1, bf1);
    stage_half(Bn, Bnxt, 1, t);
    asm volatile("s_waitcnt vmcnt(6)" ::: "memory");
    BAR();
    MFMA_Q(0, 1, bf1);
    GFENCE;
    BAR();
    // ph2: Q11
    LOAD_A(1);
    stage_half(An, Anxt, 1, t);
    BAR();
    MFMA_Q(1, 1, bf1);
    GFENCE;
    BAR();
    // ph3: Q10
    asm volatile("s_waitcnt vmcnt(4)" ::: "memory");
    BAR();
    MFMA_Q(1, 0, bf0);
    GFENCE;
    BAR();
  }
  {  // peeled last tile (kt = 15)
    const u16t* Acur = Al[1];
    const u16t* Bcur = Bl[1];
    LOAD_A(0);
    LOAD_B(0, bf0);
    asm volatile("s_waitcnt vmcnt(2)" ::: "memory");
    BAR();
    MFMA_Q(0, 0, bf0);
    GFENCE;
    BAR();
    LOAD_B(1, bf1);
    asm volatile("s_waitcnt vmcnt(0)" ::: "memory");
    BAR();
    MFMA_Q(0, 1, bf1);
    GFENCE;
    BAR();
    LOAD_A(1);
    BAR();
    MFMA_Q(1, 1, bf1);
    GFENCE;
    BAR();
    BAR();
    MFMA_Q(1, 0, bf0);
    GFENCE;
  }

#pragma unroll
  for (int qm = 0; qm < 2; ++qm)
#pragma unroll
    for (int qn = 0; qn < 2; ++qn)
#pragma unroll
      for (int mi = 0; mi < 4; ++mi)
#pragma unroll
        for (int ni = 0; ni < 2; ++ni)
#pragma unroll
          for (int j = 0; j < 4; ++j) {
            int row = M0 + qm * 128 + wr2 * 64 + mi * 16 + g * 4 + j;
            int col = N0 + qn * 128 + wc2 * 32 + ni * 16 + l16;
            C[(size_t)row * EMB + col] = acc[qm][qn][mi][ni][j];
          }
}

// ---------------- launch ----------------------------------------------------
extern "C" void kernel_launch(void* const* d_in, const int* in_sizes, int n_in,
                              void* d_out, int out_size, void* d_ws, size_t ws_size,
                              hipStream_t stream) {
  const float* query = (const float*)d_in[0];
  const float* Wq = (const float*)d_in[1];
  const float* Wk = (const float*)d_in[2];
  const float* Wv = (const float*)d_in[3];
  const float* Wo = (const float*)d_in[4];
  float* out = (float*)d_out;
  char* ws = (char*)d_ws;

  // workspace carve (bytes)
  u16t* WoT     = (u16t*)(ws);                 //  2,097,152
  u16t* WqT     = (u16t*)(ws + 2097152);       //    131,072
  u16t* WkT     = (u16t*)(ws + 2228224);       //    131,072
  u16t* WvT     = (u16t*)(ws + 2359296);       //    131,072
  u16t* phiq    = (u16t*)(ws + 2490368);       // 33,554,432  [bh][s][64]
  float* kvpart = (float*)(ws + 36044800);     //  8,388,608  [512][4096]
  float* kspart = (float*)(ws + 44433408);     //    131,072
  float* ksum_g = (float*)(ws + 44564480);     //     16,384
  u16t* W2T     = (u16t*)(ws + 44580864);      //  8,388,608  [b][e][k]
  u16t* phiq2   = (u16t*)(ws + 52969472);      // 33,554,432  [s][1024]
  // total ~86.5 MB

  la_wprep<<<304, 256, 0, stream>>>(Wq, Wk, Wv, Wo, WqT, WkT, WvT, WoT);
  la_kvq5<<<512, 256, 0, stream>>>(query, WqT, WkT, WvT, phiq, kvpart, kspart);
  la_red3<<<NBH, 256, 0, stream>>>(kvpart, kspart, WoT, ksum_g, W2T);
  la_scale<<<1024, 256, 0, stream>>>(phiq, ksum_g, phiq2);
  la_gemm9<<<256, 512, 0, stream>>>(phiq2, W2T, out);
}